// Round 2
// baseline (8531.973 us; speedup 1.0000x reference)
//
#include <hip/hip_runtime.h>

#define IN_DIM 128
#define NCLS 40

// ---------------- degree / norm ----------------

__global__ __launch_bounds__(256) void deg_kernel(const int* __restrict__ src, const int* __restrict__ dst,
                                                  int* __restrict__ ds, int* __restrict__ dd, int E) {
    int e = blockIdx.x * 256 + threadIdx.x;
    if (e < E) {
        atomicAdd(&ds[src[e]], 1);
        atomicAdd(&dd[dst[e]], 1);
    }
}

__global__ __launch_bounds__(256) void norm_kernel(const int* __restrict__ ds, const int* __restrict__ dd,
                                                   float* __restrict__ ns, float* __restrict__ nd, int N) {
    int i = blockIdx.x * 256 + threadIdx.x;
    if (i < N) {
        ns[i] = ds[i] > 0 ? rsqrtf((float)ds[i]) : 0.f;
        nd[i] = dd[i] > 0 ? rsqrtf((float)dd[i]) : 0.f;
    }
}

// ---------------- edge scatter-add: agg[dst] += x[src] * ns[src] ----------------
// D4 = number of float4 chunks per feature row

template<int D4>
__global__ __launch_bounds__(256) void scatter_kernel(const float* __restrict__ x, const int* __restrict__ src,
                                                      const int* __restrict__ dst, const float* __restrict__ ns,
                                                      float* __restrict__ agg, int total) {
    int t = blockIdx.x * 256 + threadIdx.x;
    if (t >= total) return;
    int e = t / D4;
    int c = t - e * D4;
    int s = src[e], d = dst[e];
    float4 v = ((const float4*)x)[(size_t)s * D4 + c];
    float sc = ns[s];
    float* p = agg + ((size_t)d * D4 + c) * 4;
    atomicAdd(p + 0, v.x * sc);
    atomicAdd(p + 1, v.y * sc);
    atomicAdd(p + 2, v.z * sc);
    atomicAdd(p + 3, v.w * sc);
}

// ---------------- GEMM 128 -> 128 with fused norm_dst scale, bias, optional relu ----------------
// out[i][j] = relu( (A[i][:] * nd[i]) @ W + bias[j] )
// block: 32 rows x 64 cols; grid = (ceil(N/32), 2)

__device__ __forceinline__ void fma4(float4& acc, float s, const float4& wv) {
    acc.x = fmaf(s, wv.x, acc.x);
    acc.y = fmaf(s, wv.y, acc.y);
    acc.z = fmaf(s, wv.z, acc.z);
    acc.w = fmaf(s, wv.w, acc.w);
}

template<int RELU>
__global__ __launch_bounds__(256) void gemm128_kernel(const float* __restrict__ A, const float* __restrict__ nd,
                                                      const float* __restrict__ W, const float* __restrict__ bias,
                                                      float* __restrict__ out, int N) {
    __shared__ float Ws[128 * 64];   // W[k][col0 + 0..63]
    __shared__ float As[32][128];
    int t = threadIdx.x;
    int row0 = blockIdx.x * 32;
    int col0 = blockIdx.y * 64;

    // stage W column panel: 128 x 16 float4 = 2048 float4, 8 per thread
    {
        const float4* Wg = (const float4*)W;
        float4* Ws4 = (float4*)Ws;
#pragma unroll
        for (int i = 0; i < 8; ++i) {
            int idx = t + 256 * i;     // 0..2047
            int k = idx >> 4;
            int c = idx & 15;
            Ws4[k * 16 + c] = Wg[k * 32 + (col0 >> 2) + c];
        }
    }
    // stage A tile (scaled by nd): 32 x 32 float4 = 1024 float4, 4 per thread
    {
#pragma unroll
        for (int i = 0; i < 4; ++i) {
            int idx = t + 256 * i;     // 0..1023
            int r = idx >> 5;
            int c = idx & 31;
            int gr = row0 + r;
            float4 v = make_float4(0.f, 0.f, 0.f, 0.f);
            float s = 0.f;
            if (gr < N) { v = ((const float4*)A)[(size_t)gr * 32 + c]; s = nd[gr]; }
            v.x *= s; v.y *= s; v.z *= s; v.w *= s;
            ((float4*)As[r])[c] = v;
        }
    }
    __syncthreads();

    int cg = t & 15;   // col group (float4) within 64 cols
    int rl = t >> 4;   // 0..15 ; rows rl and rl+16
    float4 acc0 = make_float4(0.f, 0.f, 0.f, 0.f);
    float4 acc1 = make_float4(0.f, 0.f, 0.f, 0.f);
    const float4* Ws4 = (const float4*)Ws;
#pragma unroll
    for (int k4 = 0; k4 < 32; ++k4) {
        float4 w0 = Ws4[(k4 * 4 + 0) * 16 + cg];
        float4 w1 = Ws4[(k4 * 4 + 1) * 16 + cg];
        float4 w2 = Ws4[(k4 * 4 + 2) * 16 + cg];
        float4 w3 = Ws4[(k4 * 4 + 3) * 16 + cg];
        float4 a0 = ((const float4*)As[rl])[k4];
        float4 a1 = ((const float4*)As[rl + 16])[k4];
        fma4(acc0, a0.x, w0); fma4(acc0, a0.y, w1); fma4(acc0, a0.z, w2); fma4(acc0, a0.w, w3);
        fma4(acc1, a1.x, w0); fma4(acc1, a1.y, w1); fma4(acc1, a1.z, w2); fma4(acc1, a1.w, w3);
    }

    float4 bb = ((const float4*)(bias + col0))[cg];
#pragma unroll
    for (int m = 0; m < 2; ++m) {
        int r = rl + 16 * m;
        int gr = row0 + r;
        if (gr < N) {
            float4 acc = (m == 0) ? acc0 : acc1;
            float4 o;
            o.x = acc.x + bb.x; o.y = acc.y + bb.y; o.z = acc.z + bb.z; o.w = acc.w + bb.w;
            if (RELU) {
                o.x = fmaxf(o.x, 0.f); o.y = fmaxf(o.y, 0.f);
                o.z = fmaxf(o.z, 0.f); o.w = fmaxf(o.w, 0.f);
            }
            ((float4*)out)[(size_t)gr * 32 + (col0 >> 2) + cg] = o;
        }
    }
}

// ---------------- GEMM 128 -> 40, no bias (bias applied after aggregation) ----------------

__global__ __launch_bounds__(256) void gemm40_kernel(const float* __restrict__ A, const float* __restrict__ W,
                                                     float* __restrict__ y, int N) {
    __shared__ float Ws[128 * NCLS];
    int t = threadIdx.x;
    for (int i = t; i < 128 * NCLS; i += 256) Ws[i] = W[i];
    __syncthreads();
    int e = blockIdx.x * 256 + t;
    if (e >= N * NCLS) return;
    int i = e / NCLS;
    int j = e - i * NCLS;
    const float* a = A + (size_t)i * 128;
    float acc = 0.f;
#pragma unroll
    for (int k = 0; k < 128; ++k) acc = fmaf(a[k], Ws[k * NCLS + j], acc);
    y[e] = acc;
}

// ---------------- final: out = out * nd[i] + b2[j] ----------------

__global__ __launch_bounds__(256) void finish_kernel(float* __restrict__ out, const float* __restrict__ nd,
                                                     const float* __restrict__ b2, int N) {
    int t = blockIdx.x * 256 + threadIdx.x;
    if (t < N * NCLS) {
        int i = t / NCLS;
        int j = t - i * NCLS;
        out[t] = out[t] * nd[i] + b2[j];
    }
}

extern "C" void kernel_launch(void* const* d_in, const int* in_sizes, int n_in,
                              void* d_out, int out_size, void* d_ws, size_t ws_size,
                              hipStream_t stream) {
    const float* x  = (const float*)d_in[0];
    const int* src  = (const int*)d_in[1];
    const int* dst  = (const int*)d_in[2];
    const float* W0 = (const float*)d_in[3];
    const float* b0 = (const float*)d_in[4];
    const float* W1 = (const float*)d_in[5];
    const float* b1 = (const float*)d_in[6];
    const float* W2 = (const float*)d_in[7];
    const float* b2 = (const float*)d_in[8];
    float* out = (float*)d_out;

    int N = in_sizes[0] / IN_DIM;
    int E = in_sizes[1];

    float* base = (float*)d_ws;
    float* ns   = base;
    float* ndn  = base + N;
    int* dsg    = (int*)(base + 2 * (size_t)N);
    int* ddg    = (int*)(base + 3 * (size_t)N);
    float* bufA = base + 4 * (size_t)N;             // N x 128
    float* bufB = bufA + (size_t)N * 128;           // N x 128

    // degrees + norms
    (void)hipMemsetAsync(dsg, 0, 2 * (size_t)N * sizeof(int), stream);
    deg_kernel<<<(E + 255) / 256, 256, 0, stream>>>(src, dst, dsg, ddg, E);
    norm_kernel<<<(N + 255) / 256, 256, 0, stream>>>(dsg, ddg, ns, ndn, N);

    int tot128 = E * 32;
    dim3 g1((N + 31) / 32, 2);

    // layer 0: agg = scatter(x * ns) ; h0 = relu((agg*nd) @ W0 + b0)
    (void)hipMemsetAsync(bufA, 0, (size_t)N * 128 * sizeof(float), stream);
    scatter_kernel<32><<<(tot128 + 255) / 256, 256, 0, stream>>>(x, src, dst, ns, bufA, tot128);
    gemm128_kernel<1><<<g1, 256, 0, stream>>>(bufA, ndn, W0, b0, bufB, N);

    // layer 1
    (void)hipMemsetAsync(bufA, 0, (size_t)N * 128 * sizeof(float), stream);
    scatter_kernel<32><<<(tot128 + 255) / 256, 256, 0, stream>>>(bufB, src, dst, ns, bufA, tot128);
    gemm128_kernel<1><<<g1, 256, 0, stream>>>(bufA, ndn, W1, b1, bufB, N);

    // layer 2: y = h1 @ W2 (128->40), then aggregate in 40-d, then *nd + b2
    gemm40_kernel<<<(N * NCLS + 255) / 256, 256, 0, stream>>>(bufB, W2, bufA, N);
    (void)hipMemsetAsync(out, 0, (size_t)N * NCLS * sizeof(float), stream);
    int tot40 = E * 10;
    scatter_kernel<10><<<(tot40 + 255) / 256, 256, 0, stream>>>(bufA, src, dst, ns, out, tot40);
    finish_kernel<<<(N * NCLS + 255) / 256, 256, 0, stream>>>(out, ndn, b2, N);
}

// Round 3
// 2650.929 us; speedup vs baseline: 3.2185x; 3.2185x over previous
//
#include <hip/hip_runtime.h>

#define IN_DIM 128
#define NCLS 40

// ---------------- degree / norm ----------------

__global__ __launch_bounds__(256) void deg_kernel(const int* __restrict__ src, const int* __restrict__ dst,
                                                  int* __restrict__ ds, int* __restrict__ dd, int E) {
    int e = blockIdx.x * 256 + threadIdx.x;
    if (e < E) {
        atomicAdd(&ds[src[e]], 1);
        atomicAdd(&dd[dst[e]], 1);
    }
}

__global__ __launch_bounds__(256) void norm_kernel(const int* __restrict__ ds, const int* __restrict__ dd,
                                                   float* __restrict__ ns, float* __restrict__ nd, int N) {
    int i = blockIdx.x * 256 + threadIdx.x;
    if (i < N) {
        ns[i] = ds[i] > 0 ? rsqrtf((float)ds[i]) : 0.f;
        nd[i] = dd[i] > 0 ? rsqrtf((float)dd[i]) : 0.f;
    }
}

// ---------------- exclusive scan of in-degrees -> row_ptr (3-kernel hierarchical) ----------------
// chunk = 1024 elements per block (256 threads x 4)

__global__ __launch_bounds__(256) void scan_partial(const int* __restrict__ dd, int* __restrict__ bsums, int N) {
    __shared__ int sd[256];
    int t = threadIdx.x;
    int base = blockIdx.x * 1024 + t * 4;
    int s = 0;
#pragma unroll
    for (int k = 0; k < 4; ++k) { int i = base + k; if (i < N) s += dd[i]; }
    sd[t] = s;
    __syncthreads();
    for (int off = 128; off > 0; off >>= 1) {
        if (t < off) sd[t] += sd[t + off];
        __syncthreads();
    }
    if (t == 0) bsums[blockIdx.x] = sd[0];
}

__global__ void scan_bsums(int* __restrict__ bsums, int nb) {
    if (threadIdx.x == 0 && blockIdx.x == 0) {
        int acc = 0;
        for (int i = 0; i < nb; ++i) { int v = bsums[i]; bsums[i] = acc; acc += v; }
    }
}

__global__ __launch_bounds__(256) void scan_final(const int* __restrict__ dd, const int* __restrict__ bsums,
                                                  int* __restrict__ cursor, int N) {
    __shared__ int sd[256];
    int t = threadIdx.x;
    int base = blockIdx.x * 1024 + t * 4;
    int v[4]; int s = 0;
#pragma unroll
    for (int k = 0; k < 4; ++k) { int i = base + k; v[k] = (i < N) ? dd[i] : 0; s += v[k]; }
    sd[t] = s;
    __syncthreads();
    // Hillis-Steele inclusive scan of per-thread sums
    for (int off = 1; off < 256; off <<= 1) {
        int u = (t >= off) ? sd[t - off] : 0;
        __syncthreads();
        sd[t] += u;
        __syncthreads();
    }
    int excl = sd[t] - s + bsums[blockIdx.x];
#pragma unroll
    for (int k = 0; k < 4; ++k) {
        int i = base + k;
        if (i < N) cursor[i] = excl;
        excl += v[k];
    }
}

// ---------------- CSR fill: cursor[i] becomes inclusive prefix afterwards ----------------

__global__ __launch_bounds__(256) void fill_csr(const int* __restrict__ src, const int* __restrict__ dst,
                                                int* __restrict__ cursor, int* __restrict__ csr, int E) {
    int e = blockIdx.x * 256 + threadIdx.x;
    if (e < E) {
        int slot = atomicAdd(&cursor[dst[e]], 1);
        csr[slot] = src[e];
    }
}

// ---------------- gather aggregation: agg[r] = sum_{s in-neighbors} ns[s] * x[s]  (128-d) ----------
// one wave (64 lanes) per dst row; lane holds float2

__global__ __launch_bounds__(256) void gather128(const float* __restrict__ x, const int* __restrict__ csr,
                                                 const int* __restrict__ cursor, const float* __restrict__ ns,
                                                 float* __restrict__ agg, int N) {
    int t = threadIdx.x;
    int lane = t & 63;
    int r = blockIdx.x * 4 + (t >> 6);
    if (r >= N) return;
    int start = r ? cursor[r - 1] : 0;
    int end = cursor[r];
    float accx = 0.f, accy = 0.f;
    const float2* xf = (const float2*)x;
    for (int base = start; base < end; base += 64) {
        int idx = 0;
        if (base + lane < end) idx = csr[base + lane];
        int cnt = min(64, end - base);
        for (int k = 0; k < cnt; ++k) {
            int s = __shfl(idx, k);
            float sc = ns[s];
            float2 v = xf[(size_t)s * 64 + lane];
            accx = fmaf(v.x, sc, accx);
            accy = fmaf(v.y, sc, accy);
        }
    }
    float2 o; o.x = accx; o.y = accy;
    ((float2*)agg)[(size_t)r * 64 + lane] = o;
}

// ---------------- gather 40-d + fused *nd + b2 -> out ----------------

__global__ __launch_bounds__(256) void gather40_finish(const float* __restrict__ y, const int* __restrict__ csr,
                                                       const int* __restrict__ cursor, const float* __restrict__ ns,
                                                       const float* __restrict__ nd, const float* __restrict__ b2,
                                                       float* __restrict__ out, int N) {
    int t = threadIdx.x;
    int lane = t & 63;
    int r = blockIdx.x * 4 + (t >> 6);
    if (r >= N) return;
    int start = r ? cursor[r - 1] : 0;
    int end = cursor[r];
    float acc = 0.f;
    for (int base = start; base < end; base += 64) {
        int idx = 0;
        if (base + lane < end) idx = csr[base + lane];
        int cnt = min(64, end - base);
        for (int k = 0; k < cnt; ++k) {
            int s = __shfl(idx, k);
            if (lane < NCLS) acc = fmaf(y[(size_t)s * NCLS + lane], ns[s], acc);
        }
    }
    if (lane < NCLS) out[(size_t)r * NCLS + lane] = acc * nd[r] + b2[lane];
}

// ---------------- GEMM 128 -> 128 with fused norm_dst scale, bias, relu ----------------

__device__ __forceinline__ void fma4(float4& acc, float s, const float4& wv) {
    acc.x = fmaf(s, wv.x, acc.x);
    acc.y = fmaf(s, wv.y, acc.y);
    acc.z = fmaf(s, wv.z, acc.z);
    acc.w = fmaf(s, wv.w, acc.w);
}

template<int RELU>
__global__ __launch_bounds__(256) void gemm128_kernel(const float* __restrict__ A, const float* __restrict__ nd,
                                                      const float* __restrict__ W, const float* __restrict__ bias,
                                                      float* __restrict__ out, int N) {
    __shared__ float Ws[128 * 64];   // W[k][col0 + 0..63]
    __shared__ float As[32][128];
    int t = threadIdx.x;
    int row0 = blockIdx.x * 32;
    int col0 = blockIdx.y * 64;

    {
        const float4* Wg = (const float4*)W;
        float4* Ws4 = (float4*)Ws;
#pragma unroll
        for (int i = 0; i < 8; ++i) {
            int idx = t + 256 * i;
            int k = idx >> 4;
            int c = idx & 15;
            Ws4[k * 16 + c] = Wg[k * 32 + (col0 >> 2) + c];
        }
    }
    {
#pragma unroll
        for (int i = 0; i < 4; ++i) {
            int idx = t + 256 * i;
            int r = idx >> 5;
            int c = idx & 31;
            int gr = row0 + r;
            float4 v = make_float4(0.f, 0.f, 0.f, 0.f);
            float s = 0.f;
            if (gr < N) { v = ((const float4*)A)[(size_t)gr * 32 + c]; s = nd[gr]; }
            v.x *= s; v.y *= s; v.z *= s; v.w *= s;
            ((float4*)As[r])[c] = v;
        }
    }
    __syncthreads();

    int cg = t & 15;
    int rl = t >> 4;
    float4 acc0 = make_float4(0.f, 0.f, 0.f, 0.f);
    float4 acc1 = make_float4(0.f, 0.f, 0.f, 0.f);
    const float4* Ws4 = (const float4*)Ws;
#pragma unroll
    for (int k4 = 0; k4 < 32; ++k4) {
        float4 w0 = Ws4[(k4 * 4 + 0) * 16 + cg];
        float4 w1 = Ws4[(k4 * 4 + 1) * 16 + cg];
        float4 w2 = Ws4[(k4 * 4 + 2) * 16 + cg];
        float4 w3 = Ws4[(k4 * 4 + 3) * 16 + cg];
        float4 a0 = ((const float4*)As[rl])[k4];
        float4 a1 = ((const float4*)As[rl + 16])[k4];
        fma4(acc0, a0.x, w0); fma4(acc0, a0.y, w1); fma4(acc0, a0.z, w2); fma4(acc0, a0.w, w3);
        fma4(acc1, a1.x, w0); fma4(acc1, a1.y, w1); fma4(acc1, a1.z, w2); fma4(acc1, a1.w, w3);
    }

    float4 bb = ((const float4*)(bias + col0))[cg];
#pragma unroll
    for (int m = 0; m < 2; ++m) {
        int r = rl + 16 * m;
        int gr = row0 + r;
        if (gr < N) {
            float4 acc = (m == 0) ? acc0 : acc1;
            float4 o;
            o.x = acc.x + bb.x; o.y = acc.y + bb.y; o.z = acc.z + bb.z; o.w = acc.w + bb.w;
            if (RELU) {
                o.x = fmaxf(o.x, 0.f); o.y = fmaxf(o.y, 0.f);
                o.z = fmaxf(o.z, 0.f); o.w = fmaxf(o.w, 0.f);
            }
            ((float4*)out)[(size_t)gr * 32 + (col0 >> 2) + cg] = o;
        }
    }
}

// ---------------- GEMM 128 -> 40, no bias (bias fused after aggregation) ----------------

__global__ __launch_bounds__(256) void gemm40_kernel(const float* __restrict__ A, const float* __restrict__ W,
                                                     float* __restrict__ y, int N) {
    __shared__ float Ws[128 * NCLS];
    int t = threadIdx.x;
    for (int i = t; i < 128 * NCLS; i += 256) Ws[i] = W[i];
    __syncthreads();
    int e = blockIdx.x * 256 + t;
    if (e >= N * NCLS) return;
    int i = e / NCLS;
    int j = e - i * NCLS;
    const float* a = A + (size_t)i * 128;
    float acc = 0.f;
#pragma unroll
    for (int k = 0; k < 128; ++k) acc = fmaf(a[k], Ws[k * NCLS + j], acc);
    y[e] = acc;
}

extern "C" void kernel_launch(void* const* d_in, const int* in_sizes, int n_in,
                              void* d_out, int out_size, void* d_ws, size_t ws_size,
                              hipStream_t stream) {
    const float* x  = (const float*)d_in[0];
    const int* src  = (const int*)d_in[1];
    const int* dst  = (const int*)d_in[2];
    const float* W0 = (const float*)d_in[3];
    const float* b0 = (const float*)d_in[4];
    const float* W1 = (const float*)d_in[5];
    const float* b1 = (const float*)d_in[6];
    const float* W2 = (const float*)d_in[7];
    const float* b2 = (const float*)d_in[8];
    float* out = (float*)d_out;

    int N = in_sizes[0] / IN_DIM;
    int E = in_sizes[1];

    float* base = (float*)d_ws;
    float* ns   = base;                       // N
    float* ndn  = base + (size_t)N;           // N
    int* dsg    = (int*)(base + 2 * (size_t)N);
    int* ddg    = (int*)(base + 3 * (size_t)N);
    int* cursor = (int*)(base + 4 * (size_t)N);
    int* bsums  = (int*)(base + 5 * (size_t)N);          // 1024
    int* csr    = (int*)(base + 5 * (size_t)N + 1024);   // E
    float* bufA = base + 5 * (size_t)N + 1024 + (size_t)E;   // N x 128
    float* bufB = bufA + (size_t)N * 128;                    // N x 128

    int nb = (N + 1023) / 1024;

    // degrees + norms
    (void)hipMemsetAsync(dsg, 0, 2 * (size_t)N * sizeof(int), stream);
    deg_kernel<<<(E + 255) / 256, 256, 0, stream>>>(src, dst, dsg, ddg, E);
    norm_kernel<<<(N + 255) / 256, 256, 0, stream>>>(dsg, ddg, ns, ndn, N);

    // CSR by dst
    scan_partial<<<nb, 256, 0, stream>>>(ddg, bsums, N);
    scan_bsums<<<1, 64, 0, stream>>>(bsums, nb);
    scan_final<<<nb, 256, 0, stream>>>(ddg, bsums, cursor, N);
    fill_csr<<<(E + 255) / 256, 256, 0, stream>>>(src, dst, cursor, csr, E);
    // after fill, cursor[i] = inclusive prefix -> row range [cursor[i-1], cursor[i])

    dim3 g1((N + 31) / 32, 2);
    int gblk = (N + 3) / 4;

    // layer 0
    gather128<<<gblk, 256, 0, stream>>>(x, csr, cursor, ns, bufA, N);
    gemm128_kernel<1><<<g1, 256, 0, stream>>>(bufA, ndn, W0, b0, bufB, N);

    // layer 1
    gather128<<<gblk, 256, 0, stream>>>(bufB, csr, cursor, ns, bufA, N);
    gemm128_kernel<1><<<g1, 256, 0, stream>>>(bufA, ndn, W1, b1, bufB, N);

    // layer 2: y = h1 @ W2, gather in 40-d with fused nd/b2
    gemm40_kernel<<<(N * NCLS + 255) / 256, 256, 0, stream>>>(bufB, W2, bufA, N);
    gather40_finish<<<gblk, 256, 0, stream>>>(bufA, csr, cursor, ns, ndn, b2, out, N);
}

// Round 4
// 789.718 us; speedup vs baseline: 10.8038x; 3.3568x over previous
//
#include <hip/hip_runtime.h>

#define IN_DIM 128
#define NCLS 40

// ---------------- degree / norm ----------------

__global__ __launch_bounds__(256) void deg_kernel(const int* __restrict__ src, const int* __restrict__ dst,
                                                  int* __restrict__ ds, int* __restrict__ dd, int E) {
    int e = blockIdx.x * 256 + threadIdx.x;
    if (e < E) {
        atomicAdd(&ds[src[e]], 1);
        atomicAdd(&dd[dst[e]], 1);
    }
}

__global__ __launch_bounds__(256) void norm_kernel(const int* __restrict__ ds, const int* __restrict__ dd,
                                                   float* __restrict__ ns, float* __restrict__ nd, int N) {
    int i = blockIdx.x * 256 + threadIdx.x;
    if (i < N) {
        ns[i] = ds[i] > 0 ? rsqrtf((float)ds[i]) : 0.f;
        nd[i] = dd[i] > 0 ? rsqrtf((float)dd[i]) : 0.f;
    }
}

// ---------------- exclusive scan of in-degrees -> row_ptr ----------------

__global__ __launch_bounds__(256) void scan_partial(const int* __restrict__ dd, int* __restrict__ bsums, int N) {
    __shared__ int sd[256];
    int t = threadIdx.x;
    int base = blockIdx.x * 1024 + t * 4;
    int s = 0;
#pragma unroll
    for (int k = 0; k < 4; ++k) { int i = base + k; if (i < N) s += dd[i]; }
    sd[t] = s;
    __syncthreads();
    for (int off = 128; off > 0; off >>= 1) {
        if (t < off) sd[t] += sd[t + off];
        __syncthreads();
    }
    if (t == 0) bsums[blockIdx.x] = sd[0];
}

__global__ void scan_bsums(int* __restrict__ bsums, int nb) {
    if (threadIdx.x == 0 && blockIdx.x == 0) {
        int acc = 0;
        for (int i = 0; i < nb; ++i) { int v = bsums[i]; bsums[i] = acc; acc += v; }
    }
}

__global__ __launch_bounds__(256) void scan_final(const int* __restrict__ dd, const int* __restrict__ bsums,
                                                  int* __restrict__ cursor, int N) {
    __shared__ int sd[256];
    int t = threadIdx.x;
    int base = blockIdx.x * 1024 + t * 4;
    int v[4]; int s = 0;
#pragma unroll
    for (int k = 0; k < 4; ++k) { int i = base + k; v[k] = (i < N) ? dd[i] : 0; s += v[k]; }
    sd[t] = s;
    __syncthreads();
    for (int off = 1; off < 256; off <<= 1) {
        int u = (t >= off) ? sd[t - off] : 0;
        __syncthreads();
        sd[t] += u;
        __syncthreads();
    }
    int excl = sd[t] - s + bsums[blockIdx.x];
#pragma unroll
    for (int k = 0; k < 4; ++k) {
        int i = base + k;
        if (i < N) cursor[i] = excl;
        excl += v[k];
    }
}

__global__ __launch_bounds__(256) void fill_csr(const int* __restrict__ src, const int* __restrict__ dst,
                                                int* __restrict__ cursor, int* __restrict__ csr, int E) {
    int e = blockIdx.x * 256 + threadIdx.x;
    if (e < E) {
        int slot = atomicAdd(&cursor[dst[e]], 1);
        csr[slot] = src[e];
    }
}

// ---------------- gather aggregation (128-d): one wave per dst row ----------------

__global__ __launch_bounds__(256) void gather128(const float* __restrict__ x, const int* __restrict__ csr,
                                                 const int* __restrict__ cursor, const float* __restrict__ ns,
                                                 float* __restrict__ agg, int N) {
    int t = threadIdx.x;
    int lane = t & 63;
    int r = blockIdx.x * 4 + (t >> 6);
    if (r >= N) return;
    int start = r ? cursor[r - 1] : 0;
    int end = cursor[r];
    float accx = 0.f, accy = 0.f;
    const float2* xf = (const float2*)x;
    for (int base = start; base < end; base += 64) {
        int idx = 0;
        if (base + lane < end) idx = csr[base + lane];
        int cnt = min(64, end - base);
        for (int k = 0; k < cnt; ++k) {
            int s = __shfl(idx, k);
            float sc = ns[s];
            float2 v = xf[(size_t)s * 64 + lane];
            accx = fmaf(v.x, sc, accx);
            accy = fmaf(v.y, sc, accy);
        }
    }
    float2 o; o.x = accx; o.y = accy;
    ((float2*)agg)[(size_t)r * 64 + lane] = o;
}

// ---------------- gather 40-d + fused *nd + b2 -> out ----------------

__global__ __launch_bounds__(256) void gather40_finish(const float* __restrict__ y, const int* __restrict__ csr,
                                                       const int* __restrict__ cursor, const float* __restrict__ ns,
                                                       const float* __restrict__ nd, const float* __restrict__ b2,
                                                       float* __restrict__ out, int N) {
    int t = threadIdx.x;
    int lane = t & 63;
    int r = blockIdx.x * 4 + (t >> 6);
    if (r >= N) return;
    int start = r ? cursor[r - 1] : 0;
    int end = cursor[r];
    float acc = 0.f;
    for (int base = start; base < end; base += 64) {
        int idx = 0;
        if (base + lane < end) idx = csr[base + lane];
        int cnt = min(64, end - base);
        for (int k = 0; k < cnt; ++k) {
            int s = __shfl(idx, k);
            if (lane < NCLS) acc = fmaf(y[(size_t)s * NCLS + lane], ns[s], acc);
        }
    }
    if (lane < NCLS) out[(size_t)r * NCLS + lane] = acc * nd[r] + b2[lane];
}

// ---------------- GEMM 128 -> 128 (fused nd scale, bias, relu) ----------------
// block: 64 rows x 64 cols, 256 threads, each thread 4 rows x 4 cols.
// LDS: W panel 32KB + A tile (stride 132) 33KB -> 2 blocks/CU.

__device__ __forceinline__ void fma4(float4& acc, float s, const float4& wv) {
    acc.x = fmaf(s, wv.x, acc.x);
    acc.y = fmaf(s, wv.y, acc.y);
    acc.z = fmaf(s, wv.z, acc.z);
    acc.w = fmaf(s, wv.w, acc.w);
}

template<int RELU>
__global__ __launch_bounds__(256) void gemm128_kernel(const float* __restrict__ A, const float* __restrict__ nd,
                                                      const float* __restrict__ W, const float* __restrict__ bias,
                                                      float* __restrict__ out, int N) {
    __shared__ float4 Ws4[128 * 16];   // W[k][col0/4 + 0..15]  (32 KB)
    __shared__ float  As[64 * 132];    // A[row][k], padded stride 132 (33 KB)
    int t = threadIdx.x;
    int row0 = blockIdx.x * 64;
    int col0 = blockIdx.y * 64;

    const float4* Wg = (const float4*)W;
#pragma unroll
    for (int i = 0; i < 8; ++i) {
        int idx = t + 256 * i;          // 0..2047
        int k = idx >> 4;
        int c = idx & 15;
        Ws4[idx] = Wg[k * 32 + (col0 >> 2) + c];
    }
#pragma unroll
    for (int i = 0; i < 8; ++i) {
        int idx = t + 256 * i;          // 0..2047
        int r = idx >> 5;
        int c4 = idx & 31;
        int gr = row0 + r;
        float4 v = make_float4(0.f, 0.f, 0.f, 0.f);
        float s = 0.f;
        if (gr < N) { v = ((const float4*)A)[(size_t)gr * 32 + c4]; s = nd[gr]; }
        v.x *= s; v.y *= s; v.z *= s; v.w *= s;
        *(float4*)&As[r * 132 + c4 * 4] = v;
    }
    __syncthreads();

    int cg = t & 15;          // float4 col within panel
    int rg = t >> 4;          // 0..15 -> rows rg*4 .. rg*4+3
    int rbase = rg * 4;
    float4 acc0 = make_float4(0.f, 0.f, 0.f, 0.f);
    float4 acc1 = acc0, acc2 = acc0, acc3 = acc0;

#pragma unroll 2
    for (int k4 = 0; k4 < 32; ++k4) {
        float4 a0 = *(const float4*)&As[(rbase + 0) * 132 + k4 * 4];
        float4 a1 = *(const float4*)&As[(rbase + 1) * 132 + k4 * 4];
        float4 a2 = *(const float4*)&As[(rbase + 2) * 132 + k4 * 4];
        float4 a3 = *(const float4*)&As[(rbase + 3) * 132 + k4 * 4];
        float4 w0 = Ws4[(k4 * 4 + 0) * 16 + cg];
        float4 w1 = Ws4[(k4 * 4 + 1) * 16 + cg];
        float4 w2 = Ws4[(k4 * 4 + 2) * 16 + cg];
        float4 w3 = Ws4[(k4 * 4 + 3) * 16 + cg];
        fma4(acc0, a0.x, w0); fma4(acc0, a0.y, w1); fma4(acc0, a0.z, w2); fma4(acc0, a0.w, w3);
        fma4(acc1, a1.x, w0); fma4(acc1, a1.y, w1); fma4(acc1, a1.z, w2); fma4(acc1, a1.w, w3);
        fma4(acc2, a2.x, w0); fma4(acc2, a2.y, w1); fma4(acc2, a2.z, w2); fma4(acc2, a2.w, w3);
        fma4(acc3, a3.x, w0); fma4(acc3, a3.y, w1); fma4(acc3, a3.z, w2); fma4(acc3, a3.w, w3);
    }

    float4 bb = ((const float4*)(bias + col0))[cg];
#pragma unroll
    for (int m = 0; m < 4; ++m) {
        int gr = row0 + rbase + m;
        if (gr < N) {
            float4 acc = (m == 0) ? acc0 : (m == 1) ? acc1 : (m == 2) ? acc2 : acc3;
            float4 o;
            o.x = acc.x + bb.x; o.y = acc.y + bb.y; o.z = acc.z + bb.z; o.w = acc.w + bb.w;
            if (RELU) {
                o.x = fmaxf(o.x, 0.f); o.y = fmaxf(o.y, 0.f);
                o.z = fmaxf(o.z, 0.f); o.w = fmaxf(o.w, 0.f);
            }
            ((float4*)out)[(size_t)gr * 32 + (col0 >> 2) + cg] = o;
        }
    }
}

// ---------------- GEMM 128 -> 40, LDS-staged, no bias ----------------
// block: 32 rows x 40 cols; thread = (row, cg) with 5 cols per thread.

__global__ __launch_bounds__(256) void gemm40_kernel(const float* __restrict__ A, const float* __restrict__ W,
                                                     float* __restrict__ y, int N) {
    __shared__ float Ws[128 * NCLS];   // 20 KB
    __shared__ float As[32 * 132];     // 16.5 KB
    int t = threadIdx.x;
    int row0 = blockIdx.x * 32;

    // stage W2: 1280 float4
#pragma unroll
    for (int i = 0; i < 5; ++i) {
        int idx = t + 256 * i;
        ((float4*)Ws)[idx] = ((const float4*)W)[idx];
    }
    // stage A: 32 rows x 32 float4
#pragma unroll
    for (int i = 0; i < 4; ++i) {
        int idx = t + 256 * i;
        int r = idx >> 5;
        int c4 = idx & 31;
        int gr = row0 + r;
        float4 v = make_float4(0.f, 0.f, 0.f, 0.f);
        if (gr < N) v = ((const float4*)A)[(size_t)gr * 32 + c4];
        *(float4*)&As[r * 132 + c4 * 4] = v;
    }
    __syncthreads();

    int row = t >> 3;     // 0..31
    int cg = t & 7;       // 0..7 -> cols cg*5 .. cg*5+4
    float acc[5] = {0.f, 0.f, 0.f, 0.f, 0.f};
#pragma unroll 2
    for (int k4 = 0; k4 < 32; ++k4) {
        float4 a = *(const float4*)&As[row * 132 + k4 * 4];
#pragma unroll
        for (int j = 0; j < 4; ++j) {
            float av = (j == 0) ? a.x : (j == 1) ? a.y : (j == 2) ? a.z : a.w;
            const float* wp = &Ws[(k4 * 4 + j) * NCLS + cg * 5];
            acc[0] = fmaf(av, wp[0], acc[0]);
            acc[1] = fmaf(av, wp[1], acc[1]);
            acc[2] = fmaf(av, wp[2], acc[2]);
            acc[3] = fmaf(av, wp[3], acc[3]);
            acc[4] = fmaf(av, wp[4], acc[4]);
        }
    }
    int gr = row0 + row;
    if (gr < N) {
        float* yp = y + (size_t)gr * NCLS + cg * 5;
        yp[0] = acc[0]; yp[1] = acc[1]; yp[2] = acc[2]; yp[3] = acc[3]; yp[4] = acc[4];
    }
}

extern "C" void kernel_launch(void* const* d_in, const int* in_sizes, int n_in,
                              void* d_out, int out_size, void* d_ws, size_t ws_size,
                              hipStream_t stream) {
    const float* x  = (const float*)d_in[0];
    const int* src  = (const int*)d_in[1];
    const int* dst  = (const int*)d_in[2];
    const float* W0 = (const float*)d_in[3];
    const float* b0 = (const float*)d_in[4];
    const float* W1 = (const float*)d_in[5];
    const float* b1 = (const float*)d_in[6];
    const float* W2 = (const float*)d_in[7];
    const float* b2 = (const float*)d_in[8];
    float* out = (float*)d_out;

    int N = in_sizes[0] / IN_DIM;
    int E = in_sizes[1];

    float* base = (float*)d_ws;
    float* ns   = base;                       // N
    float* ndn  = base + (size_t)N;           // N
    int* dsg    = (int*)(base + 2 * (size_t)N);
    int* ddg    = (int*)(base + 3 * (size_t)N);
    int* cursor = (int*)(base + 4 * (size_t)N);
    int* bsums  = (int*)(base + 5 * (size_t)N);          // 1024
    int* csr    = (int*)(base + 5 * (size_t)N + 1024);   // E
    float* bufA = base + 5 * (size_t)N + 1024 + (size_t)E;   // N x 128
    float* bufB = bufA + (size_t)N * 128;                    // N x 128

    int nb = (N + 1023) / 1024;

    (void)hipMemsetAsync(dsg, 0, 2 * (size_t)N * sizeof(int), stream);
    deg_kernel<<<(E + 255) / 256, 256, 0, stream>>>(src, dst, dsg, ddg, E);
    norm_kernel<<<(N + 255) / 256, 256, 0, stream>>>(dsg, ddg, ns, ndn, N);

    scan_partial<<<nb, 256, 0, stream>>>(ddg, bsums, N);
    scan_bsums<<<1, 64, 0, stream>>>(bsums, nb);
    scan_final<<<nb, 256, 0, stream>>>(ddg, bsums, cursor, N);
    fill_csr<<<(E + 255) / 256, 256, 0, stream>>>(src, dst, cursor, csr, E);

    dim3 g1((N + 63) / 64, 2);
    int gblk = (N + 3) / 4;

    // layer 0
    gather128<<<gblk, 256, 0, stream>>>(x, csr, cursor, ns, bufA, N);
    gemm128_kernel<1><<<g1, 256, 0, stream>>>(bufA, ndn, W0, b0, bufB, N);

    // layer 1
    gather128<<<gblk, 256, 0, stream>>>(bufB, csr, cursor, ns, bufA, N);
    gemm128_kernel<1><<<g1, 256, 0, stream>>>(bufA, ndn, W1, b1, bufB, N);

    // layer 2
    gemm40_kernel<<<(N + 31) / 32, 256, 0, stream>>>(bufB, W2, bufA, N);
    gather40_finish<<<gblk, 256, 0, stream>>>(bufA, csr, cursor, ns, ndn, b2, out, N);
}

// Round 5
// 729.871 us; speedup vs baseline: 11.6897x; 1.0820x over previous
//
#include <hip/hip_runtime.h>

#define IN_DIM 128
#define NCLS 40

// ---------------- degree / norm ----------------

__global__ __launch_bounds__(256) void deg_kernel(const int* __restrict__ src, const int* __restrict__ dst,
                                                  int* __restrict__ ds, int* __restrict__ dd, int E) {
    int e = blockIdx.x * 256 + threadIdx.x;
    if (e < E) {
        atomicAdd(&ds[src[e]], 1);
        atomicAdd(&dd[dst[e]], 1);
    }
}

__global__ __launch_bounds__(256) void norm_kernel(const int* __restrict__ ds, const int* __restrict__ dd,
                                                   float* __restrict__ ns, float* __restrict__ nd, int N) {
    int i = blockIdx.x * 256 + threadIdx.x;
    if (i < N) {
        ns[i] = ds[i] > 0 ? rsqrtf((float)ds[i]) : 0.f;
        nd[i] = dd[i] > 0 ? rsqrtf((float)dd[i]) : 0.f;
    }
}

// ---------------- exclusive scan of in-degrees -> row_ptr ----------------

__global__ __launch_bounds__(256) void scan_partial(const int* __restrict__ dd, int* __restrict__ bsums, int N) {
    __shared__ int sd[256];
    int t = threadIdx.x;
    int base = blockIdx.x * 1024 + t * 4;
    int s = 0;
#pragma unroll
    for (int k = 0; k < 4; ++k) { int i = base + k; if (i < N) s += dd[i]; }
    sd[t] = s;
    __syncthreads();
    for (int off = 128; off > 0; off >>= 1) {
        if (t < off) sd[t] += sd[t + off];
        __syncthreads();
    }
    if (t == 0) bsums[blockIdx.x] = sd[0];
}

// one wave, shfl-scan in chunks of 64
__global__ void scan_bsums(int* __restrict__ bsums, int nb) {
    int lane = threadIdx.x;
    int carry = 0;
    for (int c = 0; c < nb; c += 64) {
        int i = c + lane;
        int orig = (i < nb) ? bsums[i] : 0;
        int v = orig;
#pragma unroll
        for (int off = 1; off < 64; off <<= 1) {
            int u = __shfl_up(v, off);
            if (lane >= off) v += u;
        }
        if (i < nb) bsums[i] = carry + v - orig;   // exclusive
        carry += __shfl(v, 63);
    }
}

__global__ __launch_bounds__(256) void scan_final(const int* __restrict__ dd, const int* __restrict__ bsums,
                                                  int* __restrict__ cursor, int N) {
    __shared__ int sd[256];
    int t = threadIdx.x;
    int base = blockIdx.x * 1024 + t * 4;
    int v[4]; int s = 0;
#pragma unroll
    for (int k = 0; k < 4; ++k) { int i = base + k; v[k] = (i < N) ? dd[i] : 0; s += v[k]; }
    sd[t] = s;
    __syncthreads();
    for (int off = 1; off < 256; off <<= 1) {
        int u = (t >= off) ? sd[t - off] : 0;
        __syncthreads();
        sd[t] += u;
        __syncthreads();
    }
    int excl = sd[t] - s + bsums[blockIdx.x];
#pragma unroll
    for (int k = 0; k < 4; ++k) {
        int i = base + k;
        if (i < N) cursor[i] = excl;
        excl += v[k];
    }
}

__global__ __launch_bounds__(256) void fill_csr(const int* __restrict__ src, const int* __restrict__ dst,
                                                int* __restrict__ cursor, int* __restrict__ csr, int E) {
    int e = blockIdx.x * 256 + threadIdx.x;
    if (e < E) {
        int slot = atomicAdd(&cursor[dst[e]], 1);
        csr[slot] = src[e];
    }
}

// ---------------- fused gather + GEMM layer ----------------
// block = 64 dst rows. Phase 1: 4 waves, each gathers 16 rows (one wave per row,
// lane = float2 feature chunk) into LDS A-tile (scaled by nd). Phase 2: 64x128 @ 128x128
// GEMM, W read from global (L2-resident, broadcast), bias + relu + optional ns-scale epilogue.
// WITH_SCL: multiply gathered rows by ns[src] (layer 0 only; later layers have ns folded
// into the producer's epilogue). SCALE_NS: epilogue multiplies by ns[row] (pre-scales the
// NEXT layer's gather input).

__device__ __forceinline__ void fma4(float4& acc, float s, const float4& wv) {
    acc.x = fmaf(s, wv.x, acc.x);
    acc.y = fmaf(s, wv.y, acc.y);
    acc.z = fmaf(s, wv.z, acc.z);
    acc.w = fmaf(s, wv.w, acc.w);
}

template<int WITH_SCL, int SCALE_NS>
__global__ __launch_bounds__(256) void fused_layer(const float* __restrict__ x, const int* __restrict__ csr,
                                                   const int* __restrict__ cursor, const float* __restrict__ ns,
                                                   const float* __restrict__ nd, const float* __restrict__ W,
                                                   const float* __restrict__ bias, float* __restrict__ out, int N) {
    __shared__ float As[64 * 132];
    int t = threadIdx.x;
    int lane = t & 63;
    int wv = t >> 6;
    int row0 = blockIdx.x * 64;
    const float2* xf = (const float2*)x;

    // ---- gather phase ----
    for (int rr = 0; rr < 16; ++rr) {
        int r = row0 + wv * 16 + rr;
        if (r >= N) break;
        int start = r ? cursor[r - 1] : 0;
        int end = cursor[r];
        float ax = 0.f, ay = 0.f;
        for (int base = start; base < end; base += 64) {
            int cnt = min(64, end - base);
            int idx = 0; float scl = 0.f;
            if (base + lane < end) {
                idx = csr[base + lane];
                if (WITH_SCL) scl = ns[idx];
            }
            int k = 0;
            for (; k + 4 <= cnt; k += 4) {
                int s0 = __shfl(idx, k + 0);
                int s1 = __shfl(idx, k + 1);
                int s2 = __shfl(idx, k + 2);
                int s3 = __shfl(idx, k + 3);
                float2 v0 = xf[(size_t)s0 * 64 + lane];
                float2 v1 = xf[(size_t)s1 * 64 + lane];
                float2 v2 = xf[(size_t)s2 * 64 + lane];
                float2 v3 = xf[(size_t)s3 * 64 + lane];
                if (WITH_SCL) {
                    float c0 = __shfl(scl, k + 0), c1 = __shfl(scl, k + 1);
                    float c2 = __shfl(scl, k + 2), c3 = __shfl(scl, k + 3);
                    ax = fmaf(v0.x, c0, ax); ay = fmaf(v0.y, c0, ay);
                    ax = fmaf(v1.x, c1, ax); ay = fmaf(v1.y, c1, ay);
                    ax = fmaf(v2.x, c2, ax); ay = fmaf(v2.y, c2, ay);
                    ax = fmaf(v3.x, c3, ax); ay = fmaf(v3.y, c3, ay);
                } else {
                    ax += v0.x + v1.x + v2.x + v3.x;
                    ay += v0.y + v1.y + v2.y + v3.y;
                }
            }
            for (; k < cnt; ++k) {
                int s = __shfl(idx, k);
                float2 v = xf[(size_t)s * 64 + lane];
                if (WITH_SCL) {
                    float c = __shfl(scl, k);
                    ax = fmaf(v.x, c, ax); ay = fmaf(v.y, c, ay);
                } else {
                    ax += v.x; ay += v.y;
                }
            }
        }
        float sc = nd[r];
        int lr = wv * 16 + rr;
        *(float2*)&As[lr * 132 + lane * 2] = make_float2(ax * sc, ay * sc);
    }
    __syncthreads();

    // ---- GEMM phase: thread = 4 rows x 8 cols ----
    int rg = t >> 4;           // 0..15
    int cgp = t & 15;          // 0..15, cols cgp*8..+7
    int rbase = rg * 4;
    const float4* Wg = (const float4*)W;
    float4 acc[4][2];
#pragma unroll
    for (int m = 0; m < 4; ++m) {
        acc[m][0] = make_float4(0.f, 0.f, 0.f, 0.f);
        acc[m][1] = make_float4(0.f, 0.f, 0.f, 0.f);
    }
#pragma unroll 2
    for (int k4 = 0; k4 < 32; ++k4) {
        int k0 = k4 * 4;
        float4 a[4];
#pragma unroll
        for (int m = 0; m < 4; ++m) a[m] = *(const float4*)&As[(rbase + m) * 132 + k0];
        float4 w[4][2];
#pragma unroll
        for (int j = 0; j < 4; ++j) {
            w[j][0] = Wg[(k0 + j) * 32 + cgp * 2 + 0];
            w[j][1] = Wg[(k0 + j) * 32 + cgp * 2 + 1];
        }
#pragma unroll
        for (int m = 0; m < 4; ++m) {
            fma4(acc[m][0], a[m].x, w[0][0]); fma4(acc[m][1], a[m].x, w[0][1]);
            fma4(acc[m][0], a[m].y, w[1][0]); fma4(acc[m][1], a[m].y, w[1][1]);
            fma4(acc[m][0], a[m].z, w[2][0]); fma4(acc[m][1], a[m].z, w[2][1]);
            fma4(acc[m][0], a[m].w, w[3][0]); fma4(acc[m][1], a[m].w, w[3][1]);
        }
    }

    float4 bb0 = ((const float4*)bias)[cgp * 2 + 0];
    float4 bb1 = ((const float4*)bias)[cgp * 2 + 1];
#pragma unroll
    for (int m = 0; m < 4; ++m) {
        int gr = row0 + rbase + m;
        if (gr < N) {
            float4 o0, o1;
            o0.x = fmaxf(acc[m][0].x + bb0.x, 0.f); o0.y = fmaxf(acc[m][0].y + bb0.y, 0.f);
            o0.z = fmaxf(acc[m][0].z + bb0.z, 0.f); o0.w = fmaxf(acc[m][0].w + bb0.w, 0.f);
            o1.x = fmaxf(acc[m][1].x + bb1.x, 0.f); o1.y = fmaxf(acc[m][1].y + bb1.y, 0.f);
            o1.z = fmaxf(acc[m][1].z + bb1.z, 0.f); o1.w = fmaxf(acc[m][1].w + bb1.w, 0.f);
            if (SCALE_NS) {
                float s = ns[gr];
                o0.x *= s; o0.y *= s; o0.z *= s; o0.w *= s;
                o1.x *= s; o1.y *= s; o1.z *= s; o1.w *= s;
            }
            ((float4*)out)[(size_t)gr * 32 + cgp * 2 + 0] = o0;
            ((float4*)out)[(size_t)gr * 32 + cgp * 2 + 1] = o1;
        }
    }
}

// ---------------- GEMM 128 -> 40, epilogue scales by ns[row] (for the last gather) -----------

__global__ __launch_bounds__(256) void gemm40_kernel(const float* __restrict__ A, const float* __restrict__ W,
                                                     const float* __restrict__ ns, float* __restrict__ y, int N) {
    __shared__ float Ws[128 * NCLS];   // 20 KB
    __shared__ float As[32 * 132];     // 16.5 KB
    int t = threadIdx.x;
    int row0 = blockIdx.x * 32;

#pragma unroll
    for (int i = 0; i < 5; ++i) {
        int idx = t + 256 * i;
        ((float4*)Ws)[idx] = ((const float4*)W)[idx];
    }
#pragma unroll
    for (int i = 0; i < 4; ++i) {
        int idx = t + 256 * i;
        int r = idx >> 5;
        int c4 = idx & 31;
        int gr = row0 + r;
        float4 v = make_float4(0.f, 0.f, 0.f, 0.f);
        if (gr < N) v = ((const float4*)A)[(size_t)gr * 32 + c4];
        *(float4*)&As[r * 132 + c4 * 4] = v;
    }
    __syncthreads();

    int row = t >> 3;
    int cg = t & 7;
    float acc[5] = {0.f, 0.f, 0.f, 0.f, 0.f};
#pragma unroll 2
    for (int k4 = 0; k4 < 32; ++k4) {
        float4 a = *(const float4*)&As[row * 132 + k4 * 4];
#pragma unroll
        for (int j = 0; j < 4; ++j) {
            float av = (j == 0) ? a.x : (j == 1) ? a.y : (j == 2) ? a.z : a.w;
            const float* wp = &Ws[(k4 * 4 + j) * NCLS + cg * 5];
            acc[0] = fmaf(av, wp[0], acc[0]);
            acc[1] = fmaf(av, wp[1], acc[1]);
            acc[2] = fmaf(av, wp[2], acc[2]);
            acc[3] = fmaf(av, wp[3], acc[3]);
            acc[4] = fmaf(av, wp[4], acc[4]);
        }
    }
    int gr = row0 + row;
    if (gr < N) {
        float s = ns[gr];
        float* yp = y + (size_t)gr * NCLS + cg * 5;
        yp[0] = acc[0] * s; yp[1] = acc[1] * s; yp[2] = acc[2] * s;
        yp[3] = acc[3] * s; yp[4] = acc[4] * s;
    }
}

// ---------------- gather 40-d (input pre-scaled by ns) + *nd + b2 -> out ----------------

__global__ __launch_bounds__(256) void gather40_finish(const float* __restrict__ y, const int* __restrict__ csr,
                                                       const int* __restrict__ cursor, const float* __restrict__ nd,
                                                       const float* __restrict__ b2, float* __restrict__ out, int N) {
    int t = threadIdx.x;
    int lane = t & 63;
    int r = blockIdx.x * 4 + (t >> 6);
    if (r >= N) return;
    int start = r ? cursor[r - 1] : 0;
    int end = cursor[r];
    float acc = 0.f;
    for (int base = start; base < end; base += 64) {
        int cnt = min(64, end - base);
        int idx = 0;
        if (base + lane < end) idx = csr[base + lane];
        int k = 0;
        for (; k + 4 <= cnt; k += 4) {
            int s0 = __shfl(idx, k + 0);
            int s1 = __shfl(idx, k + 1);
            int s2 = __shfl(idx, k + 2);
            int s3 = __shfl(idx, k + 3);
            if (lane < NCLS) {
                float v0 = y[(size_t)s0 * NCLS + lane];
                float v1 = y[(size_t)s1 * NCLS + lane];
                float v2 = y[(size_t)s2 * NCLS + lane];
                float v3 = y[(size_t)s3 * NCLS + lane];
                acc += v0 + v1 + v2 + v3;
            }
        }
        for (; k < cnt; ++k) {
            int s = __shfl(idx, k);
            if (lane < NCLS) acc += y[(size_t)s * NCLS + lane];
        }
    }
    if (lane < NCLS) out[(size_t)r * NCLS + lane] = acc * nd[r] + b2[lane];
}

extern "C" void kernel_launch(void* const* d_in, const int* in_sizes, int n_in,
                              void* d_out, int out_size, void* d_ws, size_t ws_size,
                              hipStream_t stream) {
    const float* x  = (const float*)d_in[0];
    const int* src  = (const int*)d_in[1];
    const int* dst  = (const int*)d_in[2];
    const float* W0 = (const float*)d_in[3];
    const float* b0 = (const float*)d_in[4];
    const float* W1 = (const float*)d_in[5];
    const float* b1 = (const float*)d_in[6];
    const float* W2 = (const float*)d_in[7];
    const float* b2 = (const float*)d_in[8];
    float* out = (float*)d_out;

    int N = in_sizes[0] / IN_DIM;
    int E = in_sizes[1];

    float* base = (float*)d_ws;
    float* ns   = base;                       // N
    float* ndn  = base + (size_t)N;           // N
    int* dsg    = (int*)(base + 2 * (size_t)N);
    int* ddg    = (int*)(base + 3 * (size_t)N);
    int* cursor = (int*)(base + 4 * (size_t)N);
    int* bsums  = (int*)(base + 5 * (size_t)N);          // 1024
    int* csr    = (int*)(base + 5 * (size_t)N + 1024);   // E
    float* bufA = base + 5 * (size_t)N + 1024 + (size_t)E;   // N x 128
    float* bufB = bufA + (size_t)N * 128;                    // N x 128

    int nb = (N + 1023) / 1024;

    (void)hipMemsetAsync(dsg, 0, 2 * (size_t)N * sizeof(int), stream);
    deg_kernel<<<(E + 255) / 256, 256, 0, stream>>>(src, dst, dsg, ddg, E);
    norm_kernel<<<(N + 255) / 256, 256, 0, stream>>>(dsg, ddg, ns, ndn, N);

    scan_partial<<<nb, 256, 0, stream>>>(ddg, bsums, N);
    scan_bsums<<<1, 64, 0, stream>>>(bsums, nb);
    scan_final<<<nb, 256, 0, stream>>>(ddg, bsums, cursor, N);
    fill_csr<<<(E + 255) / 256, 256, 0, stream>>>(src, dst, cursor, csr, E);

    int gblk64 = (N + 63) / 64;
    int gblk4  = (N + 3) / 4;

    // layer 0: gather(x * ns) -> *nd -> @W0+b0 -> relu -> *ns  (pre-scale for next gather)
    fused_layer<1, 1><<<gblk64, 256, 0, stream>>>(x, csr, cursor, ns, ndn, W0, b0, bufB, N);
    // layer 1: gather(bufB) -> *nd -> @W1+b1 -> relu
    fused_layer<0, 0><<<gblk64, 256, 0, stream>>>(bufB, csr, cursor, ns, ndn, W1, b1, bufA, N);
    // layer 2: y = (h1 @ W2) * ns -> gather40 -> *nd + b2
    gemm40_kernel<<<(N + 31) / 32, 256, 0, stream>>>(bufA, W2, ns, bufB, N);
    gather40_finish<<<gblk4, 256, 0, stream>>>(bufB, csr, cursor, ndn, b2, out, N);
}

// Round 6
// 723.622 us; speedup vs baseline: 11.7906x; 1.0086x over previous
//
#include <hip/hip_runtime.h>

#define IN_DIM 128
#define NCLS 40

// ---------------- degree / norm ----------------

__global__ __launch_bounds__(256) void deg_kernel(const int* __restrict__ src, const int* __restrict__ dst,
                                                  int* __restrict__ ds, int* __restrict__ dd, int E) {
    int e = blockIdx.x * 256 + threadIdx.x;
    if (e < E) {
        atomicAdd(&ds[src[e]], 1);
        atomicAdd(&dd[dst[e]], 1);
    }
}

__global__ __launch_bounds__(256) void norm_kernel(const int* __restrict__ ds, const int* __restrict__ dd,
                                                   float* __restrict__ ns, float* __restrict__ nd, int N) {
    int i = blockIdx.x * 256 + threadIdx.x;
    if (i < N) {
        ns[i] = ds[i] > 0 ? rsqrtf((float)ds[i]) : 0.f;
        nd[i] = dd[i] > 0 ? rsqrtf((float)dd[i]) : 0.f;
    }
}

// ---------------- exclusive scan of in-degrees -> row_ptr ----------------

__global__ __launch_bounds__(256) void scan_partial(const int* __restrict__ dd, int* __restrict__ bsums, int N) {
    __shared__ int sd[256];
    int t = threadIdx.x;
    int base = blockIdx.x * 1024 + t * 4;
    int s = 0;
#pragma unroll
    for (int k = 0; k < 4; ++k) { int i = base + k; if (i < N) s += dd[i]; }
    sd[t] = s;
    __syncthreads();
    for (int off = 128; off > 0; off >>= 1) {
        if (t < off) sd[t] += sd[t + off];
        __syncthreads();
    }
    if (t == 0) bsums[blockIdx.x] = sd[0];
}

__global__ void scan_bsums(int* __restrict__ bsums, int nb) {
    int lane = threadIdx.x;
    int carry = 0;
    for (int c = 0; c < nb; c += 64) {
        int i = c + lane;
        int orig = (i < nb) ? bsums[i] : 0;
        int v = orig;
#pragma unroll
        for (int off = 1; off < 64; off <<= 1) {
            int u = __shfl_up(v, off);
            if (lane >= off) v += u;
        }
        if (i < nb) bsums[i] = carry + v - orig;   // exclusive
        carry += __shfl(v, 63);
    }
}

__global__ __launch_bounds__(256) void scan_final(const int* __restrict__ dd, const int* __restrict__ bsums,
                                                  int* __restrict__ cursor, int N) {
    __shared__ int sd[256];
    int t = threadIdx.x;
    int base = blockIdx.x * 1024 + t * 4;
    int v[4]; int s = 0;
#pragma unroll
    for (int k = 0; k < 4; ++k) { int i = base + k; v[k] = (i < N) ? dd[i] : 0; s += v[k]; }
    sd[t] = s;
    __syncthreads();
    for (int off = 1; off < 256; off <<= 1) {
        int u = (t >= off) ? sd[t - off] : 0;
        __syncthreads();
        sd[t] += u;
        __syncthreads();
    }
    int excl = sd[t] - s + bsums[blockIdx.x];
#pragma unroll
    for (int k = 0; k < 4; ++k) {
        int i = base + k;
        if (i < N) cursor[i] = excl;
        excl += v[k];
    }
}

__global__ __launch_bounds__(256) void fill_csr(const int* __restrict__ src, const int* __restrict__ dst,
                                                int* __restrict__ cursor, int* __restrict__ csr, int E) {
    int e = blockIdx.x * 256 + threadIdx.x;
    if (e < E) {
        int slot = atomicAdd(&cursor[dst[e]], 1);
        csr[slot] = src[e];
    }
}

// ---------------- small helpers ----------------

__device__ __forceinline__ void fma4(float4& acc, float s, const float4& wv) {
    acc.x = fmaf(s, wv.x, acc.x);
    acc.y = fmaf(s, wv.y, acc.y);
    acc.z = fmaf(s, wv.z, acc.z);
    acc.w = fmaf(s, wv.w, acc.w);
}

__device__ __forceinline__ float4 shfl_xor4(const float4& v, int m) {
    float4 r;
    r.x = __shfl_xor(v.x, m);
    r.y = __shfl_xor(v.y, m);
    r.z = __shfl_xor(v.z, m);
    r.w = __shfl_xor(v.w, m);
    return r;
}

__device__ __forceinline__ void addr4(float4& a, const float4& b) {
    a.x += b.x; a.y += b.y; a.z += b.z; a.w += b.w;
}

// ---------------- fused gather + GEMM layer ----------------
// block = 64 dst rows. Gather phase: 4 waves x 16 rows; within a wave,
// 8 edge-slots (g=lane>>3) x 8 feature-chunks (c=lane&7, 64 B each) -> 32
// independent dwordx4 loads in flight, no inner-loop shfl; 3-round shfl_xor
// reduce over edge slots per row. GEMM phase unchanged (W from L2).

template<int WITH_SCL, int SCALE_NS>
__global__ __launch_bounds__(256) void fused_layer(const float* __restrict__ x, const int* __restrict__ csr,
                                                   const int* __restrict__ cursor, const float* __restrict__ ns,
                                                   const float* __restrict__ nd, const float* __restrict__ W,
                                                   const float* __restrict__ bias, float* __restrict__ out, int N) {
    __shared__ float As[64 * 132];
    int t = threadIdx.x;
    int lane = t & 63;
    int wv = t >> 6;
    int row0 = blockIdx.x * 64;
    int g = lane >> 3;     // edge slot 0..7
    int c = lane & 7;      // feature chunk: floats [c*16, c*16+16)
    const float4* xf4 = (const float4*)x;

    // ---- gather phase ----
    for (int rr = 0; rr < 16; ++rr) {
        int r = row0 + wv * 16 + rr;
        if (r >= N) break;
        int start = r ? cursor[r - 1] : 0;
        int end = cursor[r];
        float4 a0 = make_float4(0.f, 0.f, 0.f, 0.f);
        float4 a1 = a0, a2 = a0, a3 = a0;
        for (int base = start; base < end; base += 8) {
            int e = base + g;
            int idx = 0; float scl = 0.f;
            if (e < end) {
                idx = csr[e];
                scl = WITH_SCL ? ns[idx] : 1.0f;
            }
            const float4* xp = xf4 + (size_t)idx * 32 + c * 4;
            float4 v0 = xp[0];
            float4 v1 = xp[1];
            float4 v2 = xp[2];
            float4 v3 = xp[3];
            fma4(a0, scl, v0); fma4(a1, scl, v1);
            fma4(a2, scl, v2); fma4(a3, scl, v3);
        }
        // reduce across edge slots (lane bits 3,4,5)
#pragma unroll
        for (int m = 8; m <= 32; m <<= 1) {
            addr4(a0, shfl_xor4(a0, m));
            addr4(a1, shfl_xor4(a1, m));
            addr4(a2, shfl_xor4(a2, m));
            addr4(a3, shfl_xor4(a3, m));
        }
        if (g == 0) {
            float sc = nd[r];
            float* dp = &As[(wv * 16 + rr) * 132 + c * 16];
            a0.x *= sc; a0.y *= sc; a0.z *= sc; a0.w *= sc;
            a1.x *= sc; a1.y *= sc; a1.z *= sc; a1.w *= sc;
            a2.x *= sc; a2.y *= sc; a2.z *= sc; a2.w *= sc;
            a3.x *= sc; a3.y *= sc; a3.z *= sc; a3.w *= sc;
            *(float4*)(dp + 0)  = a0;
            *(float4*)(dp + 4)  = a1;
            *(float4*)(dp + 8)  = a2;
            *(float4*)(dp + 12) = a3;
        }
    }
    __syncthreads();

    // ---- GEMM phase: thread = 4 rows x 8 cols ----
    int rg = t >> 4;
    int cgp = t & 15;
    int rbase = rg * 4;
    const float4* Wg = (const float4*)W;
    float4 acc[4][2];
#pragma unroll
    for (int m = 0; m < 4; ++m) {
        acc[m][0] = make_float4(0.f, 0.f, 0.f, 0.f);
        acc[m][1] = make_float4(0.f, 0.f, 0.f, 0.f);
    }
#pragma unroll 2
    for (int k4 = 0; k4 < 32; ++k4) {
        int k0 = k4 * 4;
        float4 a[4];
#pragma unroll
        for (int m = 0; m < 4; ++m) a[m] = *(const float4*)&As[(rbase + m) * 132 + k0];
        float4 w[4][2];
#pragma unroll
        for (int j = 0; j < 4; ++j) {
            w[j][0] = Wg[(k0 + j) * 32 + cgp * 2 + 0];
            w[j][1] = Wg[(k0 + j) * 32 + cgp * 2 + 1];
        }
#pragma unroll
        for (int m = 0; m < 4; ++m) {
            fma4(acc[m][0], a[m].x, w[0][0]); fma4(acc[m][1], a[m].x, w[0][1]);
            fma4(acc[m][0], a[m].y, w[1][0]); fma4(acc[m][1], a[m].y, w[1][1]);
            fma4(acc[m][0], a[m].z, w[2][0]); fma4(acc[m][1], a[m].z, w[2][1]);
            fma4(acc[m][0], a[m].w, w[3][0]); fma4(acc[m][1], a[m].w, w[3][1]);
        }
    }

    float4 bb0 = ((const float4*)bias)[cgp * 2 + 0];
    float4 bb1 = ((const float4*)bias)[cgp * 2 + 1];
#pragma unroll
    for (int m = 0; m < 4; ++m) {
        int gr = row0 + rbase + m;
        if (gr < N) {
            float4 o0, o1;
            o0.x = fmaxf(acc[m][0].x + bb0.x, 0.f); o0.y = fmaxf(acc[m][0].y + bb0.y, 0.f);
            o0.z = fmaxf(acc[m][0].z + bb0.z, 0.f); o0.w = fmaxf(acc[m][0].w + bb0.w, 0.f);
            o1.x = fmaxf(acc[m][1].x + bb1.x, 0.f); o1.y = fmaxf(acc[m][1].y + bb1.y, 0.f);
            o1.z = fmaxf(acc[m][1].z + bb1.z, 0.f); o1.w = fmaxf(acc[m][1].w + bb1.w, 0.f);
            if (SCALE_NS) {
                float s = ns[gr];
                o0.x *= s; o0.y *= s; o0.z *= s; o0.w *= s;
                o1.x *= s; o1.y *= s; o1.z *= s; o1.w *= s;
            }
            ((float4*)out)[(size_t)gr * 32 + cgp * 2 + 0] = o0;
            ((float4*)out)[(size_t)gr * 32 + cgp * 2 + 1] = o1;
        }
    }
}

// ---------------- GEMM 128 -> 40, epilogue scales by ns[row]; output stride 64 (padded) ------

__global__ __launch_bounds__(256) void gemm40_kernel(const float* __restrict__ A, const float* __restrict__ W,
                                                     const float* __restrict__ ns, float* __restrict__ y, int N) {
    __shared__ float Ws[128 * NCLS];   // 20 KB
    __shared__ float As[32 * 132];     // 16.5 KB
    int t = threadIdx.x;
    int row0 = blockIdx.x * 32;

#pragma unroll
    for (int i = 0; i < 5; ++i) {
        int idx = t + 256 * i;
        ((float4*)Ws)[idx] = ((const float4*)W)[idx];
    }
#pragma unroll
    for (int i = 0; i < 4; ++i) {
        int idx = t + 256 * i;
        int r = idx >> 5;
        int c4 = idx & 31;
        int gr = row0 + r;
        float4 v = make_float4(0.f, 0.f, 0.f, 0.f);
        if (gr < N) v = ((const float4*)A)[(size_t)gr * 32 + c4];
        *(float4*)&As[r * 132 + c4 * 4] = v;
    }
    __syncthreads();

    int row = t >> 3;
    int cg = t & 7;
    float acc[5] = {0.f, 0.f, 0.f, 0.f, 0.f};
#pragma unroll 2
    for (int k4 = 0; k4 < 32; ++k4) {
        float4 a = *(const float4*)&As[row * 132 + k4 * 4];
#pragma unroll
        for (int j = 0; j < 4; ++j) {
            float av = (j == 0) ? a.x : (j == 1) ? a.y : (j == 2) ? a.z : a.w;
            const float* wp = &Ws[(k4 * 4 + j) * NCLS + cg * 5];
            acc[0] = fmaf(av, wp[0], acc[0]);
            acc[1] = fmaf(av, wp[1], acc[1]);
            acc[2] = fmaf(av, wp[2], acc[2]);
            acc[3] = fmaf(av, wp[3], acc[3]);
            acc[4] = fmaf(av, wp[4], acc[4]);
        }
    }
    int gr = row0 + row;
    if (gr < N) {
        float s = ns[gr];
        float* yp = y + (size_t)gr * 64 + cg * 5;    // padded stride 64
        yp[0] = acc[0] * s; yp[1] = acc[1] * s; yp[2] = acc[2] * s;
        yp[3] = acc[3] * s; yp[4] = acc[4] * s;
    }
}

// ---------------- gather 40-d (input pre-scaled by ns, stride 64) + *nd + b2 -> out ----------
// 8 edge slots x 8 feature chunks (8 floats each); only chunks 0..4 are real.

__global__ __launch_bounds__(256) void gather40_finish(const float* __restrict__ y, const int* __restrict__ csr,
                                                       const int* __restrict__ cursor, const float* __restrict__ nd,
                                                       const float* __restrict__ b2, float* __restrict__ out, int N) {
    int t = threadIdx.x;
    int lane = t & 63;
    int r = blockIdx.x * 4 + (t >> 6);
    if (r >= N) return;
    int g = lane >> 3;
    int c = lane & 7;
    float4 b20 = make_float4(0.f, 0.f, 0.f, 0.f), b21 = b20;
    if (c < 5) {
        b20 = ((const float4*)b2)[c * 2 + 0];
        b21 = ((const float4*)b2)[c * 2 + 1];
    }
    int start = r ? cursor[r - 1] : 0;
    int end = cursor[r];
    float4 a0 = make_float4(0.f, 0.f, 0.f, 0.f), a1 = a0;
    const float4* yf4 = (const float4*)y;
    for (int base = start; base < end; base += 8) {
        int e = base + g;
        int idx = 0; float scl = 0.f;
        if (e < end) { idx = csr[e]; scl = 1.0f; }
        const float4* yp = yf4 + (size_t)idx * 16 + c * 2;
        float4 v0 = yp[0];
        float4 v1 = yp[1];
        fma4(a0, scl, v0);
        fma4(a1, scl, v1);
    }
#pragma unroll
    for (int m = 8; m <= 32; m <<= 1) {
        addr4(a0, shfl_xor4(a0, m));
        addr4(a1, shfl_xor4(a1, m));
    }
    if (g == 0 && c < 5) {
        float s = nd[r];
        float4 o0, o1;
        o0.x = fmaf(a0.x, s, b20.x); o0.y = fmaf(a0.y, s, b20.y);
        o0.z = fmaf(a0.z, s, b20.z); o0.w = fmaf(a0.w, s, b20.w);
        o1.x = fmaf(a1.x, s, b21.x); o1.y = fmaf(a1.y, s, b21.y);
        o1.z = fmaf(a1.z, s, b21.z); o1.w = fmaf(a1.w, s, b21.w);
        float* op = out + (size_t)r * NCLS + c * 8;
        *(float4*)(op + 0) = o0;
        *(float4*)(op + 4) = o1;
    }
}

extern "C" void kernel_launch(void* const* d_in, const int* in_sizes, int n_in,
                              void* d_out, int out_size, void* d_ws, size_t ws_size,
                              hipStream_t stream) {
    const float* x  = (const float*)d_in[0];
    const int* src  = (const int*)d_in[1];
    const int* dst  = (const int*)d_in[2];
    const float* W0 = (const float*)d_in[3];
    const float* b0 = (const float*)d_in[4];
    const float* W1 = (const float*)d_in[5];
    const float* b1 = (const float*)d_in[6];
    const float* W2 = (const float*)d_in[7];
    const float* b2 = (const float*)d_in[8];
    float* out = (float*)d_out;

    int N = in_sizes[0] / IN_DIM;
    int E = in_sizes[1];

    float* base = (float*)d_ws;
    float* ns   = base;                       // N
    float* ndn  = base + (size_t)N;           // N
    int* dsg    = (int*)(base + 2 * (size_t)N);
    int* ddg    = (int*)(base + 3 * (size_t)N);
    int* cursor = (int*)(base + 4 * (size_t)N);
    int* bsums  = (int*)(base + 5 * (size_t)N);          // 1024
    int* csr    = (int*)(base + 5 * (size_t)N + 1024);   // E
    float* bufA = base + 5 * (size_t)N + 1024 + (size_t)E;   // N x 128
    float* bufB = bufA + (size_t)N * 128;                    // N x 128 (y uses stride 64)

    int nb = (N + 1023) / 1024;

    (void)hipMemsetAsync(dsg, 0, 2 * (size_t)N * sizeof(int), stream);
    deg_kernel<<<(E + 255) / 256, 256, 0, stream>>>(src, dst, dsg, ddg, E);
    norm_kernel<<<(N + 255) / 256, 256, 0, stream>>>(dsg, ddg, ns, ndn, N);

    scan_partial<<<nb, 256, 0, stream>>>(ddg, bsums, N);
    scan_bsums<<<1, 64, 0, stream>>>(bsums, nb);
    scan_final<<<nb, 256, 0, stream>>>(ddg, bsums, cursor, N);
    fill_csr<<<(E + 255) / 256, 256, 0, stream>>>(src, dst, cursor, csr, E);

    int gblk64 = (N + 63) / 64;
    int gblk4  = (N + 3) / 4;

    // layer 0: gather(x * ns) -> *nd -> @W0+b0 -> relu -> *ns
    fused_layer<1, 1><<<gblk64, 256, 0, stream>>>(x, csr, cursor, ns, ndn, W0, b0, bufB, N);
    // layer 1: gather(bufB) -> *nd -> @W1+b1 -> relu
    fused_layer<0, 0><<<gblk64, 256, 0, stream>>>(bufB, csr, cursor, ns, ndn, W1, b1, bufA, N);
    // layer 2: y = (h1 @ W2) * ns (stride 64) -> gather40 -> *nd + b2
    gemm40_kernel<<<(N + 31) / 32, 256, 0, stream>>>(bufA, W2, ns, bufB, N);
    gather40_finish<<<gblk4, 256, 0, stream>>>(bufB, csr, cursor, ndn, b2, out, N);
}

// Round 7
// 636.910 us; speedup vs baseline: 13.3959x; 1.1361x over previous
//
#include <hip/hip_runtime.h>
#include <hip/hip_fp16.h>

#define IN_DIM 128
#define NCLS 40

// ---------------- degree / norm ----------------

__global__ __launch_bounds__(256) void deg_kernel(const int* __restrict__ src, const int* __restrict__ dst,
                                                  int* __restrict__ ds, int* __restrict__ dd, int E) {
    int e = blockIdx.x * 256 + threadIdx.x;
    if (e < E) {
        atomicAdd(&ds[src[e]], 1);
        atomicAdd(&dd[dst[e]], 1);
    }
}

__global__ __launch_bounds__(256) void norm_kernel(const int* __restrict__ ds, const int* __restrict__ dd,
                                                   float* __restrict__ ns, float* __restrict__ nd, int N) {
    int i = blockIdx.x * 256 + threadIdx.x;
    if (i < N) {
        ns[i] = ds[i] > 0 ? rsqrtf((float)ds[i]) : 0.f;
        nd[i] = dd[i] > 0 ? rsqrtf((float)dd[i]) : 0.f;
    }
}

// ---------------- exclusive scan of in-degrees -> row_ptr ----------------

__global__ __launch_bounds__(256) void scan_partial(const int* __restrict__ dd, int* __restrict__ bsums, int N) {
    __shared__ int sd[256];
    int t = threadIdx.x;
    int base = blockIdx.x * 1024 + t * 4;
    int s = 0;
#pragma unroll
    for (int k = 0; k < 4; ++k) { int i = base + k; if (i < N) s += dd[i]; }
    sd[t] = s;
    __syncthreads();
    for (int off = 128; off > 0; off >>= 1) {
        if (t < off) sd[t] += sd[t + off];
        __syncthreads();
    }
    if (t == 0) bsums[blockIdx.x] = sd[0];
}

__global__ void scan_bsums(int* __restrict__ bsums, int nb) {
    int lane = threadIdx.x;
    int carry = 0;
    for (int c = 0; c < nb; c += 64) {
        int i = c + lane;
        int orig = (i < nb) ? bsums[i] : 0;
        int v = orig;
#pragma unroll
        for (int off = 1; off < 64; off <<= 1) {
            int u = __shfl_up(v, off);
            if (lane >= off) v += u;
        }
        if (i < nb) bsums[i] = carry + v - orig;   // exclusive
        carry += __shfl(v, 63);
    }
}

__global__ __launch_bounds__(256) void scan_final(const int* __restrict__ dd, const int* __restrict__ bsums,
                                                  int* __restrict__ cursor, int N) {
    __shared__ int sd[256];
    int t = threadIdx.x;
    int base = blockIdx.x * 1024 + t * 4;
    int v[4]; int s = 0;
#pragma unroll
    for (int k = 0; k < 4; ++k) { int i = base + k; v[k] = (i < N) ? dd[i] : 0; s += v[k]; }
    sd[t] = s;
    __syncthreads();
    for (int off = 1; off < 256; off <<= 1) {
        int u = (t >= off) ? sd[t - off] : 0;
        __syncthreads();
        sd[t] += u;
        __syncthreads();
    }
    int excl = sd[t] - s + bsums[blockIdx.x];
#pragma unroll
    for (int k = 0; k < 4; ++k) {
        int i = base + k;
        if (i < N) cursor[i] = excl;
        excl += v[k];
    }
}

__global__ __launch_bounds__(256) void fill_csr(const int* __restrict__ src, const int* __restrict__ dst,
                                                int* __restrict__ cursor, int* __restrict__ csr, int E) {
    int e = blockIdx.x * 256 + threadIdx.x;
    if (e < E) {
        int slot = atomicAdd(&cursor[dst[e]], 1);
        csr[slot] = src[e];
    }
}

// ---------------- helpers ----------------

__device__ __forceinline__ float4 zero4() { return make_float4(0.f, 0.f, 0.f, 0.f); }

__device__ __forceinline__ void fma4(float4& acc, float s, const float4& wv) {
    acc.x = fmaf(s, wv.x, acc.x);
    acc.y = fmaf(s, wv.y, acc.y);
    acc.z = fmaf(s, wv.z, acc.z);
    acc.w = fmaf(s, wv.w, acc.w);
}

__device__ __forceinline__ float4 shfl_xor4(const float4& v, int m) {
    float4 r;
    r.x = __shfl_xor(v.x, m);
    r.y = __shfl_xor(v.y, m);
    r.z = __shfl_xor(v.z, m);
    r.w = __shfl_xor(v.w, m);
    return r;
}

__device__ __forceinline__ void addr4(float4& a, const float4& b) {
    a.x += b.x; a.y += b.y; a.z += b.z; a.w += b.w;
}

// accumulate 8 halves (one int4) scaled by m into two float4s
__device__ __forceinline__ void acc_h8(float4& a0, float4& a1, const int4& v, float m) {
    const __half2* h = (const __half2*)&v;
    float2 f0 = __half22float2(h[0]);
    float2 f1 = __half22float2(h[1]);
    float2 f2 = __half22float2(h[2]);
    float2 f3 = __half22float2(h[3]);
    a0.x = fmaf(f0.x, m, a0.x); a0.y = fmaf(f0.y, m, a0.y);
    a0.z = fmaf(f1.x, m, a0.z); a0.w = fmaf(f1.y, m, a0.w);
    a1.x = fmaf(f2.x, m, a1.x); a1.y = fmaf(f2.y, m, a1.y);
    a1.z = fmaf(f3.x, m, a1.z); a1.w = fmaf(f3.y, m, a1.w);
}

__device__ __forceinline__ int4 pack_h8(const float4& o0, const float4& o1) {
    int4 p;
    __half2* ph = (__half2*)&p;
    ph[0] = __float22half2_rn(make_float2(o0.x, o0.y));
    ph[1] = __float22half2_rn(make_float2(o0.z, o0.w));
    ph[2] = __float22half2_rn(make_float2(o1.x, o1.y));
    ph[3] = __float22half2_rn(make_float2(o1.z, o1.w));
    return p;
}

// ---------------- prescale: xh[i] = fp16(x[i] * ns[row]) ----------------

__global__ __launch_bounds__(256) void prescale_kernel(const float* __restrict__ x, const float* __restrict__ ns,
                                                       __half* __restrict__ xh, int N) {
    int tid = blockIdx.x * 256 + threadIdx.x;     // one per 8 floats
    if (tid >= N * 16) return;
    int row = tid >> 4;
    int c = tid & 15;
    float s = ns[row];
    const float4* xp = (const float4*)x + (size_t)row * 32 + c * 2;
    float4 v0 = xp[0], v1 = xp[1];
    v0.x *= s; v0.y *= s; v0.z *= s; v0.w *= s;
    v1.x *= s; v1.y *= s; v1.z *= s; v1.w *= s;
    ((int4*)xh)[tid] = pack_h8(v0, v1);
}

// ---------------- fused gather(fp16) + GEMM layer ----------------
// block = 64 dst rows. Gather: 4 waves x 16 rows, 2 rows interleaved per wave
// (2 independent latency chains); within a wave 4 edge-slots (g=lane>>4) x
// 16 chunks (c=lane&15, 8 halves = int4). fp32 accumulate, 2-round shfl_xor
// reduce, nd-scaled store to LDS. GEMM: thread = 4 rows x 8 cols, W from L2,
// epilogue bias+relu (+ns if SCALE_NS) -> fp16 output.

template<int SCALE_NS>
__global__ __launch_bounds__(256) void fused_layer(const __half* __restrict__ xh, const int* __restrict__ csr,
                                                   const int* __restrict__ cursor, const float* __restrict__ ns,
                                                   const float* __restrict__ nd, const float* __restrict__ W,
                                                   const float* __restrict__ bias, __half* __restrict__ out, int N) {
    __shared__ float As[64 * 132];
    int t = threadIdx.x;
    int lane = t & 63;
    int wv = t >> 6;
    int row0 = blockIdx.x * 64;
    int g = lane >> 4;     // edge slot 0..3
    int c = lane & 15;     // chunk: halves [c*8, c*8+8)
    const int4* xi = (const int4*)xh;

    // ---- gather phase: 8 row-pairs per wave ----
    for (int rr = 0; rr < 16; rr += 2) {
        int rA = row0 + wv * 16 + rr;
        int rB = rA + 1;
        int sA = 0, eA = 0, sB = 0, eB = 0;
        if (rA < N) { sA = rA ? cursor[rA - 1] : 0; eA = cursor[rA]; }
        if (rB < N) { sB = cursor[rB - 1]; eB = cursor[rB]; }
        float4 aA0 = zero4(), aA1 = zero4(), aB0 = zero4(), aB1 = zero4();
        int oA = sA, oB = sB;
        while (oA < eA || oB < eB) {
            int ea0 = oA + g, ea1 = oA + 4 + g;
            int eb0 = oB + g, eb1 = oB + 4 + g;
            float ma0 = (ea0 < eA) ? 1.f : 0.f;
            float ma1 = (ea1 < eA) ? 1.f : 0.f;
            float mb0 = (eb0 < eB) ? 1.f : 0.f;
            float mb1 = (eb1 < eB) ? 1.f : 0.f;
            int ia0 = (ea0 < eA) ? csr[ea0] : 0;
            int ia1 = (ea1 < eA) ? csr[ea1] : 0;
            int ib0 = (eb0 < eB) ? csr[eb0] : 0;
            int ib1 = (eb1 < eB) ? csr[eb1] : 0;
            int4 va0 = xi[(size_t)ia0 * 16 + c];
            int4 va1 = xi[(size_t)ia1 * 16 + c];
            int4 vb0 = xi[(size_t)ib0 * 16 + c];
            int4 vb1 = xi[(size_t)ib1 * 16 + c];
            acc_h8(aA0, aA1, va0, ma0);
            acc_h8(aA0, aA1, va1, ma1);
            acc_h8(aB0, aB1, vb0, mb0);
            acc_h8(aB0, aB1, vb1, mb1);
            oA += 8; oB += 8;
        }
        // reduce across the 4 edge slots (lane bits 4, 5)
#pragma unroll
        for (int m = 16; m <= 32; m <<= 1) {
            addr4(aA0, shfl_xor4(aA0, m));
            addr4(aA1, shfl_xor4(aA1, m));
            addr4(aB0, shfl_xor4(aB0, m));
            addr4(aB1, shfl_xor4(aB1, m));
        }
        if (g == 0) {
            if (rA < N) {
                float sc = nd[rA];
                float* dp = &As[(wv * 16 + rr) * 132 + c * 8];
                aA0.x *= sc; aA0.y *= sc; aA0.z *= sc; aA0.w *= sc;
                aA1.x *= sc; aA1.y *= sc; aA1.z *= sc; aA1.w *= sc;
                *(float4*)(dp + 0) = aA0;
                *(float4*)(dp + 4) = aA1;
            }
            if (rB < N) {
                float sc = nd[rB];
                float* dp = &As[(wv * 16 + rr + 1) * 132 + c * 8];
                aB0.x *= sc; aB0.y *= sc; aB0.z *= sc; aB0.w *= sc;
                aB1.x *= sc; aB1.y *= sc; aB1.z *= sc; aB1.w *= sc;
                *(float4*)(dp + 0) = aB0;
                *(float4*)(dp + 4) = aB1;
            }
        }
    }
    __syncthreads();

    // ---- GEMM phase: thread = 4 rows x 8 cols ----
    int rg = t >> 4;
    int cgp = t & 15;
    int rbase = rg * 4;
    const float4* Wg = (const float4*)W;
    float4 acc[4][2];
#pragma unroll
    for (int m = 0; m < 4; ++m) { acc[m][0] = zero4(); acc[m][1] = zero4(); }
#pragma unroll 2
    for (int k4 = 0; k4 < 32; ++k4) {
        int k0 = k4 * 4;
        float4 a[4];
#pragma unroll
        for (int m = 0; m < 4; ++m) a[m] = *(const float4*)&As[(rbase + m) * 132 + k0];
        float4 w[4][2];
#pragma unroll
        for (int j = 0; j < 4; ++j) {
            w[j][0] = Wg[(k0 + j) * 32 + cgp * 2 + 0];
            w[j][1] = Wg[(k0 + j) * 32 + cgp * 2 + 1];
        }
#pragma unroll
        for (int m = 0; m < 4; ++m) {
            fma4(acc[m][0], a[m].x, w[0][0]); fma4(acc[m][1], a[m].x, w[0][1]);
            fma4(acc[m][0], a[m].y, w[1][0]); fma4(acc[m][1], a[m].y, w[1][1]);
            fma4(acc[m][0], a[m].z, w[2][0]); fma4(acc[m][1], a[m].z, w[2][1]);
            fma4(acc[m][0], a[m].w, w[3][0]); fma4(acc[m][1], a[m].w, w[3][1]);
        }
    }

    float4 bb0 = ((const float4*)bias)[cgp * 2 + 0];
    float4 bb1 = ((const float4*)bias)[cgp * 2 + 1];
#pragma unroll
    for (int m = 0; m < 4; ++m) {
        int gr = row0 + rbase + m;
        if (gr < N) {
            float4 o0, o1;
            o0.x = fmaxf(acc[m][0].x + bb0.x, 0.f); o0.y = fmaxf(acc[m][0].y + bb0.y, 0.f);
            o0.z = fmaxf(acc[m][0].z + bb0.z, 0.f); o0.w = fmaxf(acc[m][0].w + bb0.w, 0.f);
            o1.x = fmaxf(acc[m][1].x + bb1.x, 0.f); o1.y = fmaxf(acc[m][1].y + bb1.y, 0.f);
            o1.z = fmaxf(acc[m][1].z + bb1.z, 0.f); o1.w = fmaxf(acc[m][1].w + bb1.w, 0.f);
            if (SCALE_NS) {
                float s = ns[gr];
                o0.x *= s; o0.y *= s; o0.z *= s; o0.w *= s;
                o1.x *= s; o1.y *= s; o1.z *= s; o1.w *= s;
            }
            ((int4*)out)[(size_t)gr * 16 + cgp] = pack_h8(o0, o1);
        }
    }
}

// ---------------- GEMM 128(fp16) -> 40, epilogue *ns -> fp16 y (stride 40 halves) ----------

__global__ __launch_bounds__(256) void gemm40_kernel(const __half* __restrict__ A, const float* __restrict__ W,
                                                     const float* __restrict__ ns, __half* __restrict__ y, int N) {
    __shared__ float Ws[128 * NCLS];   // 20 KB
    __shared__ float As[32 * 132];     // 16.5 KB
    int t = threadIdx.x;
    int row0 = blockIdx.x * 32;

#pragma unroll
    for (int i = 0; i < 5; ++i) {
        int idx = t + 256 * i;
        ((float4*)Ws)[idx] = ((const float4*)W)[idx];
    }
    // stage A (fp16 -> fp32): 32 rows x 16 int4
#pragma unroll
    for (int i = 0; i < 2; ++i) {
        int idx = t + 256 * i;        // 0..511
        int r = idx >> 4;
        int c16 = idx & 15;
        int gr = row0 + r;
        int4 v = make_int4(0, 0, 0, 0);
        if (gr < N) v = ((const int4*)A)[(size_t)gr * 16 + c16];
        const __half2* h = (const __half2*)&v;
        float2 f0 = __half22float2(h[0]);
        float2 f1 = __half22float2(h[1]);
        float2 f2 = __half22float2(h[2]);
        float2 f3 = __half22float2(h[3]);
        float* dp = &As[r * 132 + c16 * 8];
        dp[0] = f0.x; dp[1] = f0.y; dp[2] = f1.x; dp[3] = f1.y;
        dp[4] = f2.x; dp[5] = f2.y; dp[6] = f3.x; dp[7] = f3.y;
    }
    __syncthreads();

    int row = t >> 3;
    int cg = t & 7;
    float acc[5] = {0.f, 0.f, 0.f, 0.f, 0.f};
#pragma unroll 2
    for (int k4 = 0; k4 < 32; ++k4) {
        float4 a = *(const float4*)&As[row * 132 + k4 * 4];
#pragma unroll
        for (int j = 0; j < 4; ++j) {
            float av = (j == 0) ? a.x : (j == 1) ? a.y : (j == 2) ? a.z : a.w;
            const float* wp = &Ws[(k4 * 4 + j) * NCLS + cg * 5];
            acc[0] = fmaf(av, wp[0], acc[0]);
            acc[1] = fmaf(av, wp[1], acc[1]);
            acc[2] = fmaf(av, wp[2], acc[2]);
            acc[3] = fmaf(av, wp[3], acc[3]);
            acc[4] = fmaf(av, wp[4], acc[4]);
        }
    }
    int gr = row0 + row;
    if (gr < N) {
        float s = ns[gr];
        __half* yp = y + (size_t)gr * NCLS + cg * 5;
        yp[0] = __float2half_rn(acc[0] * s);
        yp[1] = __float2half_rn(acc[1] * s);
        yp[2] = __float2half_rn(acc[2] * s);
        yp[3] = __float2half_rn(acc[3] * s);
        yp[4] = __float2half_rn(acc[4] * s);
    }
}

// ---------------- gather 40-d (fp16 y, pre-scaled by ns) + *nd + b2 -> out (fp32) ----------
// 8 edge slots (g) x 8 chunks (c, 8 halves); c<5 real (row = 5 int4 = 40 halves).

__global__ __launch_bounds__(256) void gather40_finish(const __half* __restrict__ y, const int* __restrict__ csr,
                                                       const int* __restrict__ cursor, const float* __restrict__ nd,
                                                       const float* __restrict__ b2, float* __restrict__ out, int N) {
    int t = threadIdx.x;
    int lane = t & 63;
    int r = blockIdx.x * 4 + (t >> 6);
    if (r >= N) return;
    int g = lane >> 3;
    int c = lane & 7;
    int start = r ? cursor[r - 1] : 0;
    int end = cursor[r];
    float4 a0 = zero4(), a1 = zero4();
    const int4* yi = (const int4*)y;
    for (int base = start; base < end; base += 16) {
        int e0 = base + g, e1 = base + 8 + g;
        float m0 = (e0 < end) ? 1.f : 0.f;
        float m1 = (e1 < end) ? 1.f : 0.f;
        int i0 = (e0 < end) ? csr[e0] : 0;
        int i1 = (e1 < end) ? csr[e1] : 0;
        if (c < 5) {
            int4 v0 = yi[(size_t)i0 * 5 + c];
            int4 v1 = yi[(size_t)i1 * 5 + c];
            acc_h8(a0, a1, v0, m0);
            acc_h8(a0, a1, v1, m1);
        }
    }
#pragma unroll
    for (int m = 8; m <= 32; m <<= 1) {
        addr4(a0, shfl_xor4(a0, m));
        addr4(a1, shfl_xor4(a1, m));
    }
    if (g == 0 && c < 5) {
        float s = nd[r];
        float4 b20 = ((const float4*)b2)[c * 2 + 0];
        float4 b21 = ((const float4*)b2)[c * 2 + 1];
        float4 o0, o1;
        o0.x = fmaf(a0.x, s, b20.x); o0.y = fmaf(a0.y, s, b20.y);
        o0.z = fmaf(a0.z, s, b20.z); o0.w = fmaf(a0.w, s, b20.w);
        o1.x = fmaf(a1.x, s, b21.x); o1.y = fmaf(a1.y, s, b21.y);
        o1.z = fmaf(a1.z, s, b21.z); o1.w = fmaf(a1.w, s, b21.w);
        float* op = out + (size_t)r * NCLS + c * 8;
        *(float4*)(op + 0) = o0;
        *(float4*)(op + 4) = o1;
    }
}

extern "C" void kernel_launch(void* const* d_in, const int* in_sizes, int n_in,
                              void* d_out, int out_size, void* d_ws, size_t ws_size,
                              hipStream_t stream) {
    const float* x  = (const float*)d_in[0];
    const int* src  = (const int*)d_in[1];
    const int* dst  = (const int*)d_in[2];
    const float* W0 = (const float*)d_in[3];
    const float* b0 = (const float*)d_in[4];
    const float* W1 = (const float*)d_in[5];
    const float* b1 = (const float*)d_in[6];
    const float* W2 = (const float*)d_in[7];
    const float* b2 = (const float*)d_in[8];
    float* out = (float*)d_out;

    int N = in_sizes[0] / IN_DIM;
    int E = in_sizes[1];

    float* base = (float*)d_ws;
    float* ns   = base;                       // N
    float* ndn  = base + (size_t)N;           // N
    int* dsg    = (int*)(base + 2 * (size_t)N);
    int* ddg    = (int*)(base + 3 * (size_t)N);
    int* cursor = (int*)(base + 4 * (size_t)N);
    int* bsums  = (int*)(base + 5 * (size_t)N);          // 1024
    int* csr    = (int*)(base + 5 * (size_t)N + 1024);   // E
    __half* xh  = (__half*)(csr + (size_t)E);            // N x 128 halves
    __half* h0  = xh + (size_t)N * 128;                  // N x 128 halves
    __half* h1  = h0 + (size_t)N * 128;                  // N x 128 halves
    __half* yh  = h1 + (size_t)N * 128;                  // N x 40 halves

    int nb = (N + 1023) / 1024;

    (void)hipMemsetAsync(dsg, 0, 2 * (size_t)N * sizeof(int), stream);
    deg_kernel<<<(E + 255) / 256, 256, 0, stream>>>(src, dst, dsg, ddg, E);
    norm_kernel<<<(N + 255) / 256, 256, 0, stream>>>(dsg, ddg, ns, ndn, N);

    scan_partial<<<nb, 256, 0, stream>>>(ddg, bsums, N);
    scan_bsums<<<1, 64, 0, stream>>>(bsums, nb);
    scan_final<<<nb, 256, 0, stream>>>(ddg, bsums, cursor, N);
    fill_csr<<<(E + 255) / 256, 256, 0, stream>>>(src, dst, cursor, csr, E);

    // xh = fp16(x * ns)
    prescale_kernel<<<(N * 16 + 255) / 256, 256, 0, stream>>>(x, ns, xh, N);

    int gblk64 = (N + 63) / 64;
    int gblk4  = (N + 3) / 4;

    // layer 0: gather(xh) -> *nd -> @W0+b0 -> relu -> *ns -> fp16 h0
    fused_layer<1><<<gblk64, 256, 0, stream>>>(xh, csr, cursor, ns, ndn, W0, b0, h0, N);
    // layer 1: gather(h0) -> *nd -> @W1+b1 -> relu -> fp16 h1
    fused_layer<0><<<gblk64, 256, 0, stream>>>(h0, csr, cursor, ns, ndn, W1, b1, h1, N);
    // layer 2: y = (h1 @ W2) * ns (fp16, stride 40) -> gather40 -> *nd + b2
    gemm40_kernel<<<(N + 31) / 32, 256, 0, stream>>>(h1, W2, ns, yh, N);
    gather40_finish<<<gblk4, 256, 0, stream>>>(yh, csr, cursor, ndn, b2, out, N);
}